// Round 1
// baseline (355.811 us; speedup 1.0000x reference)
//
#include <hip/hip_runtime.h>

#define HID   150
#define HP    160           // padded hidden width
#define TW    320           // T row: [0,160)=A-proj, [160,320)=B-proj
#define H1S   164           // h1 LDS row stride (floats)
#define NSPAN 2000
#define DSPAN 1220
#define NPAIR 65536

// ---------------- P1: phi contribution tables (19 x 160) ----------------
// rows 0..8  : dist bin b  -> dist_emb[b] @ W1[3660:3680]  (+ b1 folded in)
// rows 9..15 : genre g     -> genre_emb[g] @ W1[3680:3700]
// rows 16..18: speaker s   -> speaker_emb[s] @ W1[3700:3720]
__global__ __launch_bounds__(256)
void phi_kernel(const float* __restrict__ de, const float* __restrict__ ge,
                const float* __restrict__ se, const float* __restrict__ W1,
                const float* __restrict__ b1, float* __restrict__ phi) {
  int t = threadIdx.x;
  for (int idx = t; idx < 19 * HP; idx += 256) {
    int row = idx / HP;
    int j = idx - row * HP;
    float v = 0.f;
    if (j < HID) {
      const float* emb;
      int w0;
      if (row < 9)       { emb = de + row * 20;        w0 = 3660; v = b1[j]; }
      else if (row < 16) { emb = ge + (row - 9) * 20;  w0 = 3680; }
      else               { emb = se + (row - 16) * 20; w0 = 3700; }
      #pragma unroll
      for (int e = 0; e < 20; ++e) v += emb[e] * W1[(w0 + e) * HID + j];
    }
    phi[idx] = v;
  }
}

// ---------------- P2: per-span projections ----------------
// T[s][j]      = sum_d g[s][d]   * W1[d][j]                       (ct = 0)
// T[s][160+j]  = sum_d g[s][d]   * W1[1220+d][j]
//              + sum_d g[s][d]^2 * W1[2440+d][j]                  (ct = 1)
// Grid: (ct=2, span-tile=32, k-chunk=4); K split -> fp32 atomicAdd into
// zero-initialized T so all 256 CUs get a block.
__global__ __launch_bounds__(256)
void span_proj(const float* __restrict__ g, const float* __restrict__ W1,
               float* __restrict__ T) {
  const int ct = blockIdx.x;   // 0: A-proj, 1: B-proj
  const int st = blockIdx.y;   // 64-span tile
  const int kc = blockIdx.z;   // k-chunk of 305

  __shared__ float gs[64 * 20];      // 64 spans x 16 k, stride 20 (2-way max)
  __shared__ float wbs[16 * HP];
  __shared__ float wcs[16 * HP];

  const int t = threadIdx.x;
  const int ty = t >> 4, tx = t & 15;

  float acc[4][10];
  #pragma unroll
  for (int i = 0; i < 4; ++i)
    #pragma unroll
    for (int c = 0; c < 10; ++c) acc[i][c] = 0.f;

  const int kbeg = kc * 305;
  const int kend = (kbeg + 305 < DSPAN) ? (kbeg + 305) : DSPAN;

  for (int k0 = kbeg; k0 < kend; k0 += 16) {
    __syncthreads();
    // stage g tile: 64 spans x 16 k
    for (int idx = t; idx < 64 * 16; idx += 256) {
      int r = idx >> 4, cc = idx & 15;
      int s = st * 64 + r, k = k0 + cc;
      gs[r * 20 + cc] = (s < NSPAN && k < kend) ? g[s * DSPAN + k] : 0.f;
    }
    // stage weight tile(s): 16 k x 160 cols (zero-padded)
    if (ct == 0) {
      for (int idx = t; idx < 16 * HP; idx += 256) {
        int kk = idx / HP, j = idx - kk * HP;
        int k = k0 + kk;
        wbs[idx] = (k < kend && j < HID) ? W1[k * HID + j] : 0.f;
      }
    } else {
      for (int idx = t; idx < 16 * HP; idx += 256) {
        int kk = idx / HP, j = idx - kk * HP;
        int k = k0 + kk;
        bool ok = (k < kend && j < HID);
        wbs[idx] = ok ? W1[(DSPAN + k) * HID + j] : 0.f;
        wcs[idx] = ok ? W1[(2 * DSPAN + k) * HID + j] : 0.f;
      }
    }
    __syncthreads();

    if (ct == 0) {
      #pragma unroll
      for (int kk4 = 0; kk4 < 16; kk4 += 4) {
        float hv[4][4];
        #pragma unroll
        for (int i = 0; i < 4; ++i) {
          float4 f = *(const float4*)&gs[(ty * 4 + i) * 20 + kk4];
          hv[i][0] = f.x; hv[i][1] = f.y; hv[i][2] = f.z; hv[i][3] = f.w;
        }
        #pragma unroll
        for (int u = 0; u < 4; ++u) {
          float w[10];
          #pragma unroll
          for (int c = 0; c < 10; ++c) w[c] = wbs[(kk4 + u) * HP + tx + 16 * c];
          #pragma unroll
          for (int i = 0; i < 4; ++i) {
            float gv = hv[i][u];
            #pragma unroll
            for (int c = 0; c < 10; ++c) acc[i][c] = fmaf(gv, w[c], acc[i][c]);
          }
        }
      }
    } else {
      #pragma unroll
      for (int kk4 = 0; kk4 < 16; kk4 += 4) {
        float hv[4][4];
        #pragma unroll
        for (int i = 0; i < 4; ++i) {
          float4 f = *(const float4*)&gs[(ty * 4 + i) * 20 + kk4];
          hv[i][0] = f.x; hv[i][1] = f.y; hv[i][2] = f.z; hv[i][3] = f.w;
        }
        #pragma unroll
        for (int u = 0; u < 4; ++u) {
          float wB[10], wC[10];
          #pragma unroll
          for (int c = 0; c < 10; ++c) {
            wB[c] = wbs[(kk4 + u) * HP + tx + 16 * c];
            wC[c] = wcs[(kk4 + u) * HP + tx + 16 * c];
          }
          #pragma unroll
          for (int i = 0; i < 4; ++i) {
            float gv = hv[i][u];
            float g2 = gv * gv;
            #pragma unroll
            for (int c = 0; c < 10; ++c)
              acc[i][c] = fmaf(gv, wB[c], fmaf(g2, wC[c], acc[i][c]));
          }
        }
      }
    }
  }

  #pragma unroll
  for (int i = 0; i < 4; ++i) {
    int s = st * 64 + ty * 4 + i;
    if (s < NSPAN) {
      #pragma unroll
      for (int c = 0; c < 10; ++c) {
        int j = tx + 16 * c;
        if (j < HID) atomicAdd(&T[s * TW + ct * HP + j], acc[i][c]);
      }
    }
  }
}

// ---------------- P3: fused pair kernel ----------------
// 64 pairs per block. h1 = relu(A[m] + B[a] + phi-lookups) in LDS,
// layer 2 via register-tiled fp32 FMA over LDS-staged W2 chunks,
// then relu + W3 dot + 16-lane shuffle reduce.
__global__ __launch_bounds__(256)
void pair_kernel(const float* __restrict__ T, const float* __restrict__ phi,
                 const float* __restrict__ W2, const float* __restrict__ b2,
                 const float* __restrict__ W3, const float* __restrict__ b3,
                 const float* __restrict__ s_m,
                 const int* __restrict__ m_ids, const int* __restrict__ a_ids,
                 const int* __restrict__ dist, const int* __restrict__ genre,
                 const int* __restrict__ spk, float* __restrict__ out) {
  __shared__ float h1s[64 * H1S];   // 41984 B
  __shared__ float w2t[16 * HP];    // 10240 B
  __shared__ float w3s[HP];
  __shared__ float b2s[HP];
  __shared__ float sm2[64];
  __shared__ int mi[64], ai[64], ob[64], og[64], os[64];

  const int t = threadIdx.x;
  const int base = blockIdx.x * 64;

  if (t < 64) {
    int p = base + t;
    int m = m_ids[p], a = a_ids[p];
    mi[t] = m; ai[t] = a;
    sm2[t] = s_m[m] + s_m[a];
    int d = dist[p];
    int b = (d >= 2) + (d >= 3) + (d >= 4) + (d >= 5) + (d >= 8) +
            (d >= 16) + (d >= 32) + (d >= 64);
    ob[t] = b * HP;
    og[t] = (9 + genre[p]) * HP;
    os[t] = (16 + spk[p]) * HP;
  }
  if (t < HP) {
    w3s[t] = (t < HID) ? W3[t] : 0.f;
    b2s[t] = (t < HID) ? b2[t] : 0.f;
  }
  float b3v = b3[0];
  __syncthreads();

  // stage 1: h1 for 64 pairs x 160 (padded cols are exact zeros)
  for (int idx = t; idx < 64 * HP; idx += 256) {
    int p = idx / HP;
    int j = idx - p * HP;
    float v = T[mi[p] * TW + j] + T[ai[p] * TW + HP + j] +
              phi[ob[p] + j] + phi[og[p] + j] + phi[os[p] + j];
    h1s[p * H1S + j] = fmaxf(v, 0.f);
  }

  // stage 2: h2 = h1 @ W2 (64x160 output tile, 4 pairs x 10 cols per thread)
  const int ty = t >> 4, tx = t & 15;
  float acc[4][10];
  #pragma unroll
  for (int i = 0; i < 4; ++i)
    #pragma unroll
    for (int c = 0; c < 10; ++c) acc[i][c] = 0.f;

  for (int kt = 0; kt < 10; ++kt) {
    __syncthreads();
    for (int idx = t; idx < 16 * HP; idx += 256) {
      int kk = idx / HP, j = idx - kk * HP;
      int k = kt * 16 + kk;
      w2t[idx] = (k < HID && j < HID) ? W2[k * HID + j] : 0.f;
    }
    __syncthreads();
    #pragma unroll
    for (int kk4 = 0; kk4 < 16; kk4 += 4) {
      float hv[4][4];
      #pragma unroll
      for (int i = 0; i < 4; ++i) {
        float4 f = *(const float4*)&h1s[(ty * 4 + i) * H1S + kt * 16 + kk4];
        hv[i][0] = f.x; hv[i][1] = f.y; hv[i][2] = f.z; hv[i][3] = f.w;
      }
      #pragma unroll
      for (int u = 0; u < 4; ++u) {
        float w[10];
        #pragma unroll
        for (int c = 0; c < 10; ++c) w[c] = w2t[(kk4 + u) * HP + tx + 16 * c];
        #pragma unroll
        for (int i = 0; i < 4; ++i) {
          float hvu = hv[i][u];
          #pragma unroll
          for (int c = 0; c < 10; ++c) acc[i][c] = fmaf(hvu, w[c], acc[i][c]);
        }
      }
    }
  }

  // stage 3: relu(h2 + b2) . W3, reduce over the 16 tx lanes
  float res[4];
  #pragma unroll
  for (int i = 0; i < 4; ++i) res[i] = 0.f;
  #pragma unroll
  for (int c = 0; c < 10; ++c) {
    int j = tx + 16 * c;
    float w3v = w3s[j];
    float b2v = b2s[j];
    #pragma unroll
    for (int i = 0; i < 4; ++i)
      res[i] += fmaxf(acc[i][c] + b2v, 0.f) * w3v;
  }
  #pragma unroll
  for (int off = 8; off >= 1; off >>= 1) {
    #pragma unroll
    for (int i = 0; i < 4; ++i) res[i] += __shfl_xor(res[i], off, 64);
  }
  if (tx == 0) {
    #pragma unroll
    for (int i = 0; i < 4; ++i) {
      int p = ty * 4 + i;
      out[base + p] = sm2[p] + res[i] + b3v;
    }
  }
}

extern "C" void kernel_launch(void* const* d_in, const int* in_sizes, int n_in,
                              void* d_out, int out_size, void* d_ws, size_t ws_size,
                              hipStream_t stream) {
  const float* g     = (const float*)d_in[0];
  const float* s_m   = (const float*)d_in[1];
  const int*   m_ids = (const int*)d_in[2];
  const int*   a_ids = (const int*)d_in[3];
  const int*   dist  = (const int*)d_in[4];
  const int*   genre = (const int*)d_in[5];
  const int*   spk   = (const int*)d_in[6];
  const float* de    = (const float*)d_in[7];
  const float* ge    = (const float*)d_in[8];
  const float* se    = (const float*)d_in[9];
  const float* W1    = (const float*)d_in[10];
  const float* b1    = (const float*)d_in[11];
  const float* W2    = (const float*)d_in[12];
  const float* b2    = (const float*)d_in[13];
  const float* W3    = (const float*)d_in[14];
  const float* b3    = (const float*)d_in[15];
  float* out = (float*)d_out;

  float* T   = (float*)d_ws;            // 2000*320 floats = 2.56 MB
  float* phi = T + NSPAN * TW;          // 19*160 floats

  hipMemsetAsync(T, 0, NSPAN * TW * sizeof(float), stream);
  phi_kernel<<<1, 256, 0, stream>>>(de, ge, se, W1, b1, phi);
  span_proj<<<dim3(2, 32, 4), 256, 0, stream>>>(g, W1, T);
  pair_kernel<<<NPAIR / 64, 256, 0, stream>>>(T, phi, W2, b2, W3, b3, s_m,
                                              m_ids, a_ids, dist, genre, spk, out);
}

// Round 2
// 165.524 us; speedup vs baseline: 2.1496x; 2.1496x over previous
//
#include <hip/hip_runtime.h>

typedef short bf16x8 __attribute__((ext_vector_type(8)));
typedef float f32x4  __attribute__((ext_vector_type(4)));

#define NSPAN 2000
#define DSPAN 1220
#define NPAIR 65536
#define HID   150
#define HP    160          // padded hidden width
#define TW    320          // T row: [0,160) A-proj, [160,320) B-proj
#define KA    2496         // padded K for span GEMM = 78*32
#define NKS   78           // k-steps of 32
#define NMT   128          // 2048/16 row tiles
#define NNT   20           // 320/16 col tiles
#define H1S   168          // h1 bf16 row stride (336 B, 16B aligned, 2-way banks)

static __device__ __forceinline__ short f2bf(float x) {
  unsigned u = __builtin_bit_cast(unsigned, x);
  u = (u + 0x7FFFu + ((u >> 16) & 1u)) >> 16;   // RNE
  return (short)u;
}

// ---------- prep_a: A_cat = [g | g^2] (2048 x 2496) in MFMA A-fragment order ----
// frag layout: offset ((mt*78+ks)*64 + l)*8 + i  <->  A[mt*16+(l&15)][ks*32+(l>>4)*8+i]
__global__ __launch_bounds__(256)
void prep_a(const float* __restrict__ g, short* __restrict__ A_fr) {
  int tid = blockIdx.x * 256 + threadIdx.x;      // 2496 blocks -> exactly 128*78*64
  int l  = tid & 63;
  int t2 = tid >> 6;
  int ks = t2 % NKS;
  int mt = t2 / NKS;
  int m  = mt * 16 + (l & 15);
  int k0 = ks * 32 + ((l >> 4) << 3);
  short v[8];
#pragma unroll
  for (int i = 0; i < 8; ++i) {
    int k = k0 + i;
    float x = 0.f;
    if (m < NSPAN) {
      if (k < DSPAN)            x = g[m * DSPAN + k];
      else if (k < 2 * DSPAN) { float y = g[m * DSPAN + k - DSPAN]; x = y * y; }
    }
    v[i] = f2bf(x);
  }
  *(bf16x8*)(A_fr + (size_t)tid * 8) = *(const bf16x8*)v;
}

// ---------- prep_small: Wc fragments + phi tables + W2 fragments ----------
// Wc (2496 x 320): rows 0..1219 = [W1a | pad | W1b | pad], rows 1220..2439 = [0 | pad | W1c | pad]
// B-frag layout: offset ((nt*78+ks)*64+l)*8+i <-> Wc[ks*32+(l>>4)*8+i][nt*16+(l&15)]
// phi (19 x 160 fp32): dist rows 0..8 (+b1), genre 9..15, speaker 16..18
// W2 frags: offset ((jt*5+ks)*64+l)*8+i <-> W2[ks*32+(l>>4)*8+i][jt*16+(l&15)]
__global__ __launch_bounds__(256)
void prep_small(const float* __restrict__ W1, const float* __restrict__ b1,
                const float* __restrict__ de, const float* __restrict__ ge,
                const float* __restrict__ se, const float* __restrict__ W2,
                short* __restrict__ Wc_fr, float* __restrict__ phi,
                short* __restrict__ W2_fr) {
  int b = blockIdx.x;
  int t = threadIdx.x;
  if (b < 390) {                       // Wc fragments: 20*78*64 = 99840 threads exact
    int tid = b * 256 + t;
    int l  = tid & 63;
    int t2 = tid >> 6;
    int ks = t2 % NKS;
    int nt = t2 / NKS;
    int n  = nt * 16 + (l & 15);
    int k0 = ks * 32 + ((l >> 4) << 3);
    short v[8];
#pragma unroll
    for (int i = 0; i < 8; ++i) {
      int k = k0 + i;
      float x = 0.f;
      if (k < DSPAN) {
        if (n < HID)                       x = W1[k * HID + n];
        else if (n >= HP && n < HP + HID)  x = W1[(DSPAN + k) * HID + (n - HP)];
      } else if (k < 2 * DSPAN) {
        if (n >= HP && n < HP + HID)       x = W1[(2 * DSPAN + (k - DSPAN)) * HID + (n - HP)];
      }
      v[i] = f2bf(x);
    }
    *(bf16x8*)(Wc_fr + (size_t)tid * 8) = *(const bf16x8*)v;
  } else if (b < 402) {                // phi: 19*160 = 3040
    int idx = (b - 390) * 256 + t;
    if (idx < 19 * HP) {
      int row = idx / HP;
      int j = idx - row * HP;
      float v = 0.f;
      if (j < HID) {
        const float* emb; int w0;
        if (row < 9)       { emb = de + row * 20;        w0 = 3660; v = b1[j]; }
        else if (row < 16) { emb = ge + (row - 9) * 20;  w0 = 3680; }
        else               { emb = se + (row - 16) * 20; w0 = 3700; }
#pragma unroll
        for (int e = 0; e < 20; ++e) v += emb[e] * W1[(w0 + e) * HID + j];
      }
      phi[idx] = v;
    }
  } else {                             // W2 fragments: 10*5*64 = 3200
    int tid = (b - 402) * 256 + t;
    if (tid < 3200) {
      int l  = tid & 63;
      int t2 = tid >> 6;
      int ks = t2 % 5;
      int jt = t2 / 5;
      int n  = jt * 16 + (l & 15);
      int k0 = ks * 32 + ((l >> 4) << 3);
      short v[8];
#pragma unroll
      for (int i = 0; i < 8; ++i) {
        int k = k0 + i;
        float x = (k < HID && n < HID) ? W2[k * HID + n] : 0.f;
        v[i] = f2bf(x);
      }
      *(bf16x8*)(W2_fr + (size_t)tid * 8) = *(const bf16x8*)v;
    }
  }
}

// ---------- span GEMM: T = A_cat @ Wc  (2048 x 320, K=2496), MFMA, no LDS ----------
// grid (5, 32); wave w of block handles rows (blockIdx.y*4+w)*16, cols blockIdx.x*64.
__global__ __launch_bounds__(256)
void span_gemm(const short* __restrict__ A_fr, const short* __restrict__ Wc_fr,
               float* __restrict__ T) {
  int t = threadIdx.x, w = t >> 6, l = t & 63;
  int mt  = blockIdx.y * 4 + w;
  int ntb = blockIdx.x * 4;
  const short* pa = A_fr + (size_t)(mt * NKS) * 512 + l * 8;
  const short* pb = Wc_fr + (size_t)(ntb * NKS) * 512 + l * 8;
  f32x4 a0 = {0.f, 0.f, 0.f, 0.f}, a1 = a0, a2 = a0, a3 = a0;
  for (int ks = 0; ks < NKS; ++ks) {
    bf16x8 a  = *(const bf16x8*)pa;
    bf16x8 b0 = *(const bf16x8*)pb;
    bf16x8 b1 = *(const bf16x8*)(pb + (size_t)NKS * 512);
    bf16x8 b2 = *(const bf16x8*)(pb + (size_t)2 * NKS * 512);
    bf16x8 b3 = *(const bf16x8*)(pb + (size_t)3 * NKS * 512);
    a0 = __builtin_amdgcn_mfma_f32_16x16x32_bf16(a, b0, a0, 0, 0, 0);
    a1 = __builtin_amdgcn_mfma_f32_16x16x32_bf16(a, b1, a1, 0, 0, 0);
    a2 = __builtin_amdgcn_mfma_f32_16x16x32_bf16(a, b2, a2, 0, 0, 0);
    a3 = __builtin_amdgcn_mfma_f32_16x16x32_bf16(a, b3, a3, 0, 0, 0);
    pa += 512; pb += 512;
  }
  int col = l & 15, row4 = (l >> 4) << 2;
  f32x4 acc[4] = {a0, a1, a2, a3};
#pragma unroll
  for (int r = 0; r < 4; ++r) {
    int m = mt * 16 + row4 + r;
    if (m < NSPAN) {
#pragma unroll
      for (int j = 0; j < 4; ++j)
        T[m * TW + (ntb + j) * 16 + col] = acc[j][r];
    }
  }
}

// ---------- pair kernel: gather h1 (fp32) -> bf16 LDS -> MFMA layer2 -> score ----
__global__ __launch_bounds__(256)
void pair_kernel(const float* __restrict__ T, const float* __restrict__ phi,
                 const short* __restrict__ W2_fr,
                 const float* __restrict__ b2, const float* __restrict__ W3,
                 const float* __restrict__ b3, const float* __restrict__ s_m,
                 const int* __restrict__ m_ids, const int* __restrict__ a_ids,
                 const int* __restrict__ dist, const int* __restrict__ genre,
                 const int* __restrict__ spk, float* __restrict__ out) {
  __shared__ short h1s[64 * H1S];
  __shared__ float w3s[HP], b2s[HP], sm2[64];
  __shared__ int mi[64], ai[64], ob[64], og[64], os[64];

  int t = threadIdx.x;
  int base = blockIdx.x * 64;

  if (t < 64) {
    int p = base + t;
    int m = m_ids[p], a = a_ids[p];
    mi[t] = m; ai[t] = a;
    sm2[t] = s_m[m] + s_m[a];
    int d = dist[p];
    int bb = (d >= 2) + (d >= 3) + (d >= 4) + (d >= 5) + (d >= 8) +
             (d >= 16) + (d >= 32) + (d >= 64);
    ob[t] = bb * HP;
    og[t] = (9 + genre[p]) * HP;
    os[t] = (16 + spk[p]) * HP;
  }
  if (t < HP) {
    w3s[t] = (t < HID) ? W3[t] : 0.f;
    b2s[t] = (t < HID) ? b2[t] : 0.f;
  }
  float b3v = b3[0];
  __syncthreads();

  // h1 = relu(A[m] + B[a] + phi lookups); padded cols (150..159) are exact zeros
  for (int idx = t; idx < 64 * HP; idx += 256) {
    int p = idx / HP;
    int j = idx - p * HP;
    float v = T[mi[p] * TW + j] + T[ai[p] * TW + HP + j] +
              phi[ob[p] + j] + phi[og[p] + j] + phi[os[p] + j];
    h1s[p * H1S + j] = f2bf(fmaxf(v, 0.f));
  }
  __syncthreads();

  int w = t >> 6, l = t & 63;
  // A-fragments: wave's 16 pairs, K=160 = 5 k-steps of 32
  const short* hrow = h1s + (w * 16 + (l & 15)) * H1S + ((l >> 4) << 3);
  bf16x8 af[5];
#pragma unroll
  for (int ks = 0; ks < 5; ++ks) af[ks] = *(const bf16x8*)(hrow + ks * 32);

  f32x4 acc[10];
#pragma unroll
  for (int jt = 0; jt < 10; ++jt) acc[jt] = {0.f, 0.f, 0.f, 0.f};

  const short* pw = W2_fr + l * 8;
#pragma unroll
  for (int jt = 0; jt < 10; ++jt) {
#pragma unroll
    for (int ks = 0; ks < 5; ++ks) {
      bf16x8 bfr = *(const bf16x8*)(pw + (size_t)(jt * 5 + ks) * 512);
      acc[jt] = __builtin_amdgcn_mfma_f32_16x16x32_bf16(af[ks], bfr, acc[jt], 0, 0, 0);
    }
  }

  // epilogue: relu(h2 + b2) . W3, reduce over 16 col-lanes
  float part[4] = {0.f, 0.f, 0.f, 0.f};
  int cl = l & 15;
#pragma unroll
  for (int jt = 0; jt < 10; ++jt) {
    int n = jt * 16 + cl;
    float w3v = w3s[n], b2v = b2s[n];
#pragma unroll
    for (int r = 0; r < 4; ++r) part[r] += fmaxf(acc[jt][r] + b2v, 0.f) * w3v;
  }
#pragma unroll
  for (int off = 8; off >= 1; off >>= 1) {
#pragma unroll
    for (int r = 0; r < 4; ++r) part[r] += __shfl_xor(part[r], off, 64);
  }
  if (cl == 0) {
    int rowb = (l >> 4) << 2;
#pragma unroll
    for (int r = 0; r < 4; ++r) {
      int p = w * 16 + rowb + r;
      out[base + p] = sm2[p] + part[r] + b3v;
    }
  }
}

extern "C" void kernel_launch(void* const* d_in, const int* in_sizes, int n_in,
                              void* d_out, int out_size, void* d_ws, size_t ws_size,
                              hipStream_t stream) {
  const float* g     = (const float*)d_in[0];
  const float* s_m   = (const float*)d_in[1];
  const int*   m_ids = (const int*)d_in[2];
  const int*   a_ids = (const int*)d_in[3];
  const int*   dist  = (const int*)d_in[4];
  const int*   genre = (const int*)d_in[5];
  const int*   spk   = (const int*)d_in[6];
  const float* de    = (const float*)d_in[7];
  const float* ge    = (const float*)d_in[8];
  const float* se    = (const float*)d_in[9];
  const float* W1    = (const float*)d_in[10];
  const float* b1    = (const float*)d_in[11];
  const float* W2    = (const float*)d_in[12];
  const float* b2    = (const float*)d_in[13];
  const float* W3    = (const float*)d_in[14];
  const float* b3    = (const float*)d_in[15];
  float* out = (float*)d_out;

  float* T     = (float*)d_ws;                    // 2000*320 f32 = 2.56 MB
  float* phi   = T + NSPAN * TW;                  // 19*160 f32
  short* A_fr  = (short*)(phi + 19 * HP);         // 128*78*64*8 bf16 = 10.22 MB
  short* Wc_fr = A_fr + (size_t)NMT * NKS * 512;  // 20*78*64*8 bf16 = 1.60 MB
  short* W2_fr = Wc_fr + (size_t)NNT * NKS * 512; // 3200*8 bf16

  prep_a<<<2496, 256, 0, stream>>>(g, A_fr);
  prep_small<<<415, 256, 0, stream>>>(W1, b1, de, ge, se, W2, Wc_fr, phi, W2_fr);
  span_gemm<<<dim3(5, 32), 256, 0, stream>>>(A_fr, Wc_fr, T);
  pair_kernel<<<NPAIR / 64, 256, 0, stream>>>(T, phi, W2_fr, b2, W3, b3, s_m,
                                              m_ids, a_ids, dist, genre, spk, out);
}

// Round 3
// 151.970 us; speedup vs baseline: 2.3413x; 1.0892x over previous
//
#include <hip/hip_runtime.h>

typedef short bf16x8 __attribute__((ext_vector_type(8)));
typedef short bf16x4 __attribute__((ext_vector_type(4)));
typedef float f32x4  __attribute__((ext_vector_type(4)));

#define NSPAN 2000
#define DSPAN 1220
#define NPAIR 65536
#define HID   150
#define HP    160          // padded hidden width
#define TW    320          // T row: [0,160) A-proj, [160,320) B-proj
#define NKS   78           // total k-steps of 32 (K = 2496 = 2 x 1248)
#define NKH   39           // k-steps per half (g half / g^2 half)
#define NMT   128          // 2048/16 row tiles
#define NNT   20           // 320/16 col tiles
#define KC    6            // k-split chunks (78 = 6*13)
#define H1S   168          // h1 bf16 row stride (336 B, 16B aligned)

static __device__ __forceinline__ short f2bf(float x) {
  unsigned u = __builtin_bit_cast(unsigned, x);
  u = (u + 0x7FFFu + ((u >> 16) & 1u)) >> 16;   // RNE
  return (short)u;
}

// ---------- prep_a: A_cat = [g pad1248 | g^2 pad1248] in MFMA A-frag order ----
// frag: offset ((mt*78+ks)*64+l)*8+i <-> A[mt*16+(l&15)][ks*32+(l>>4)*8+i]
// One g read feeds both the g frag (ks) and the g^2 frag (ks+39).
__global__ __launch_bounds__(256)
void prep_a(const float* __restrict__ g, short* __restrict__ A_fr) {
  int tid = blockIdx.x * 256 + threadIdx.x;      // 1248 blocks = 128*39*64
  int l  = tid & 63;
  int t2 = tid >> 6;
  int ks = t2 % NKH;
  int mt = t2 / NKH;
  int m  = mt * 16 + (l & 15);
  int k0 = ks * 32 + ((l >> 4) << 3);
  short v1[8], v2[8];
#pragma unroll
  for (int i = 0; i < 8; ++i) {
    int k = k0 + i;
    float x = (m < NSPAN && k < DSPAN) ? g[m * DSPAN + k] : 0.f;
    v1[i] = f2bf(x);
    v2[i] = f2bf(x * x);
  }
  size_t o1 = ((size_t)(mt * NKS + ks) * 64 + l) * 8;
  *(bf16x8*)(A_fr + o1) = *(const bf16x8*)v1;
  *(bf16x8*)(A_fr + o1 + (size_t)NKH * 512) = *(const bf16x8*)v2;
}

// ---------- prep_weights: Wc frags (LDS transpose) + phi + W2 frags ----------
// Wc (2496 x 320): k<1248: [W1a | 0 | W1b | 0] (k<1220), k>=1248: [0 | 0 | W1c | 0]
// B-frag: offset ((nt*78+ks)*64+l)*8+i <-> Wc[ks*32+(l>>4)*8+i][nt*16+(l&15)]
__global__ __launch_bounds__(256)
void prep_weights(const float* __restrict__ W1, const float* __restrict__ b1,
                  const float* __restrict__ de, const float* __restrict__ ge,
                  const float* __restrict__ se, const float* __restrict__ W2,
                  short* __restrict__ Wc_fr, float* __restrict__ phi,
                  short* __restrict__ W2_fr) {
  __shared__ short Lt[320 * 40];     // [n][kk], stride 40 shorts (80 B, 16B-aligned)
  int b = blockIdx.x;
  int t = threadIdx.x;
  if (b < NKS) {                     // 78 blocks: Wc fragments for one k-step
    int ks = b, k0 = ks * 32;
    for (int idx = t; idx < 32 * 320; idx += 256) {
      int kk = idx / 320;            // consecutive t -> consecutive n: coalesced W1 reads
      int n  = idx - kk * 320;
      int k  = k0 + kk;
      float x = 0.f;
      if (n < HID) {
        if (k < DSPAN) x = W1[k * HID + n];
      } else if (n >= HP && n < HP + HID) {
        int j = n - HP;
        if (k < DSPAN)                   x = W1[(DSPAN + k) * HID + j];
        else if (k >= 1248 && k < 2468)  x = W1[(1192 + k) * HID + j];
      }
      Lt[n * 40 + kk] = f2bf(x);
    }
    __syncthreads();
    int w = t >> 6, l = t & 63;
    int nrow = l & 15, kk8 = (l >> 4) << 3;
#pragma unroll
    for (int i = 0; i < 5; ++i) {
      int nt = w * 5 + i;
      bf16x8 v = *(const bf16x8*)&Lt[(nt * 16 + nrow) * 40 + kk8];
      *(bf16x8*)(Wc_fr + ((size_t)(nt * NKS + ks) * 64 + l) * 8) = v;
    }
  } else if (b < NKS + 13) {         // phi: 19*160 = 3040 entries
    int idx = (b - NKS) * 256 + t;
    if (idx < 19 * HP) {
      int row = idx / HP;
      int j = idx - row * HP;
      float v = 0.f;
      if (j < HID) {
        const float* emb; int w0;
        if (row < 9)       { emb = de + row * 20;        w0 = 3660; v = b1[j]; }
        else if (row < 16) { emb = ge + (row - 9) * 20;  w0 = 3680; }
        else               { emb = se + (row - 16) * 20; w0 = 3700; }
#pragma unroll
        for (int e = 0; e < 20; ++e) v += emb[e] * W1[(w0 + e) * HID + j];
      }
      phi[idx] = v;
    }
  } else {                           // W2 frags: 10*5*64 = 3200 fragment-vectors
    int tid = (b - NKS - 13) * 256 + t;
    if (tid < 3200) {
      int l  = tid & 63;
      int t2 = tid >> 6;
      int ks = t2 % 5;
      int jt = t2 / 5;
      int n  = jt * 16 + (l & 15);
      int k0 = ks * 32 + ((l >> 4) << 3);
      short v[8];
#pragma unroll
      for (int i = 0; i < 8; ++i) {
        int k = k0 + i;
        float x = (k < HID && n < HID) ? W2[k * HID + n] : 0.f;
        v[i] = f2bf(x);
      }
      *(bf16x8*)(W2_fr + (size_t)tid * 8) = *(const bf16x8*)v;
    }
  }
}

// ---------- span GEMM: T += A_cat @ Wc, K-split x6, fp32 atomicAdd ----------
__global__ __launch_bounds__(256)
void span_gemm(const short* __restrict__ A_fr, const short* __restrict__ Wc_fr,
               float* __restrict__ T) {
  int t = threadIdx.x, w = t >> 6, l = t & 63;
  int mt  = blockIdx.y * 4 + w;
  int ntb = blockIdx.x * 4;
  int ksb = blockIdx.z * 13;
  const short* pa = A_fr + ((size_t)(mt * NKS + ksb) * 64 + l) * 8;
  const short* pb = Wc_fr + ((size_t)(ntb * NKS + ksb) * 64 + l) * 8;
  f32x4 a0 = {0.f, 0.f, 0.f, 0.f}, a1 = a0, a2 = a0, a3 = a0;
#pragma unroll
  for (int ks = 0; ks < 13; ++ks) {
    bf16x8 a  = *(const bf16x8*)pa;
    bf16x8 b0 = *(const bf16x8*)pb;
    bf16x8 b1 = *(const bf16x8*)(pb + (size_t)NKS * 512);
    bf16x8 b2 = *(const bf16x8*)(pb + (size_t)2 * NKS * 512);
    bf16x8 b3 = *(const bf16x8*)(pb + (size_t)3 * NKS * 512);
    a0 = __builtin_amdgcn_mfma_f32_16x16x32_bf16(a, b0, a0, 0, 0, 0);
    a1 = __builtin_amdgcn_mfma_f32_16x16x32_bf16(a, b1, a1, 0, 0, 0);
    a2 = __builtin_amdgcn_mfma_f32_16x16x32_bf16(a, b2, a2, 0, 0, 0);
    a3 = __builtin_amdgcn_mfma_f32_16x16x32_bf16(a, b3, a3, 0, 0, 0);
    pa += 512; pb += 512;
  }
  int col = l & 15, row4 = (l >> 4) << 2;
  f32x4 acc[4] = {a0, a1, a2, a3};
#pragma unroll
  for (int r = 0; r < 4; ++r) {
    int m = mt * 16 + row4 + r;
    if (m < NSPAN) {
#pragma unroll
      for (int j = 0; j < 4; ++j)
        atomicAdd(&T[m * TW + (ntb + j) * 16 + col], acc[j][r]);
    }
  }
}

// ---------- pair kernel: gather h1 -> bf16 LDS -> MFMA layer2 -> score ----------
__global__ __launch_bounds__(256)
void pair_kernel(const float* __restrict__ T, const float* __restrict__ phi,
                 const short* __restrict__ W2_fr,
                 const float* __restrict__ b2, const float* __restrict__ W3,
                 const float* __restrict__ b3, const float* __restrict__ s_m,
                 const int* __restrict__ m_ids, const int* __restrict__ a_ids,
                 const int* __restrict__ dist, const int* __restrict__ genre,
                 const int* __restrict__ spk, float* __restrict__ out) {
  __shared__ short h1s[64 * H1S];
  __shared__ float w3s[HP], b2s[HP], sm2[64];
  __shared__ int mi[64], ai[64], ob[64], og[64], os[64];

  int t = threadIdx.x;
  int base = blockIdx.x * 64;

  if (t < 64) {
    int p = base + t;
    int m = m_ids[p], a = a_ids[p];
    mi[t] = m; ai[t] = a;
    sm2[t] = s_m[m] + s_m[a];
    int d = dist[p];
    int bb = (d >= 2) + (d >= 3) + (d >= 4) + (d >= 5) + (d >= 8) +
             (d >= 16) + (d >= 32) + (d >= 64);
    ob[t] = bb * HP;
    og[t] = (9 + genre[p]) * HP;
    os[t] = (16 + spk[p]) * HP;
  }
  if (t < HP) {
    w3s[t] = (t < HID) ? W3[t] : 0.f;
    b2s[t] = (t < HID) ? b2[t] : 0.f;
  }
  float b3v = b3[0];
  __syncthreads();

  // h1 = relu(A[m] + B[a] + phi lookups), float4-vectorized (pad cols exact 0)
  for (int idx = t; idx < 64 * 40; idx += 256) {
    int p = idx / 40;
    int j = (idx - p * 40) * 4;
    const float4 vm = *(const float4*)&T[mi[p] * TW + j];
    const float4 va = *(const float4*)&T[ai[p] * TW + HP + j];
    const float4 f1 = *(const float4*)&phi[ob[p] + j];
    const float4 f2 = *(const float4*)&phi[og[p] + j];
    const float4 f3 = *(const float4*)&phi[os[p] + j];
    bf16x4 r;
    r[0] = f2bf(fmaxf(vm.x + va.x + f1.x + f2.x + f3.x, 0.f));
    r[1] = f2bf(fmaxf(vm.y + va.y + f1.y + f2.y + f3.y, 0.f));
    r[2] = f2bf(fmaxf(vm.z + va.z + f1.z + f2.z + f3.z, 0.f));
    r[3] = f2bf(fmaxf(vm.w + va.w + f1.w + f2.w + f3.w, 0.f));
    *(bf16x4*)&h1s[p * H1S + j] = r;
  }
  __syncthreads();

  int w = t >> 6, l = t & 63;
  const short* hrow = h1s + (w * 16 + (l & 15)) * H1S + ((l >> 4) << 3);
  bf16x8 af[5];
#pragma unroll
  for (int ks = 0; ks < 5; ++ks) af[ks] = *(const bf16x8*)(hrow + ks * 32);

  f32x4 acc[10];
#pragma unroll
  for (int jt = 0; jt < 10; ++jt) acc[jt] = {0.f, 0.f, 0.f, 0.f};

  const short* pw = W2_fr + l * 8;
#pragma unroll
  for (int jt = 0; jt < 10; ++jt) {
#pragma unroll
    for (int ks = 0; ks < 5; ++ks) {
      bf16x8 bfr = *(const bf16x8*)(pw + (size_t)(jt * 5 + ks) * 512);
      acc[jt] = __builtin_amdgcn_mfma_f32_16x16x32_bf16(af[ks], bfr, acc[jt], 0, 0, 0);
    }
  }

  float part[4] = {0.f, 0.f, 0.f, 0.f};
  int cl = l & 15;
#pragma unroll
  for (int jt = 0; jt < 10; ++jt) {
    int n = jt * 16 + cl;
    float w3v = w3s[n], b2v = b2s[n];
#pragma unroll
    for (int r = 0; r < 4; ++r) part[r] += fmaxf(acc[jt][r] + b2v, 0.f) * w3v;
  }
#pragma unroll
  for (int off = 8; off >= 1; off >>= 1) {
#pragma unroll
    for (int r = 0; r < 4; ++r) part[r] += __shfl_xor(part[r], off, 64);
  }
  if (cl == 0) {
    int rowb = (l >> 4) << 2;
#pragma unroll
    for (int r = 0; r < 4; ++r) {
      int p = w * 16 + rowb + r;
      out[base + p] = sm2[p] + part[r] + b3v;
    }
  }
}

extern "C" void kernel_launch(void* const* d_in, const int* in_sizes, int n_in,
                              void* d_out, int out_size, void* d_ws, size_t ws_size,
                              hipStream_t stream) {
  const float* g     = (const float*)d_in[0];
  const float* s_m   = (const float*)d_in[1];
  const int*   m_ids = (const int*)d_in[2];
  const int*   a_ids = (const int*)d_in[3];
  const int*   dist  = (const int*)d_in[4];
  const int*   genre = (const int*)d_in[5];
  const int*   spk   = (const int*)d_in[6];
  const float* de    = (const float*)d_in[7];
  const float* ge    = (const float*)d_in[8];
  const float* se    = (const float*)d_in[9];
  const float* W1    = (const float*)d_in[10];
  const float* b1    = (const float*)d_in[11];
  const float* W2    = (const float*)d_in[12];
  const float* b2    = (const float*)d_in[13];
  const float* W3    = (const float*)d_in[14];
  const float* b3    = (const float*)d_in[15];
  float* out = (float*)d_out;

  float* T     = (float*)d_ws;                    // 2000*320 f32 = 2.56 MB
  float* phi   = T + NSPAN * TW;                  // 19*160 f32
  short* A_fr  = (short*)(phi + 19 * HP);         // 128*78*512 bf16 = 10.22 MB
  short* Wc_fr = A_fr + (size_t)NMT * NKS * 512;  // 20*78*512 bf16 = 1.60 MB
  short* W2_fr = Wc_fr + (size_t)NNT * NKS * 512; // 3200*8 bf16

  hipMemsetAsync(T, 0, NSPAN * TW * sizeof(float), stream);
  prep_a<<<1248, 256, 0, stream>>>(g, A_fr);
  prep_weights<<<NKS + 26, 256, 0, stream>>>(W1, b1, de, ge, se, W2,
                                             Wc_fr, phi, W2_fr);
  span_gemm<<<dim3(5, 32, KC), 256, 0, stream>>>(A_fr, Wc_fr, T);
  pair_kernel<<<NPAIR / 64, 256, 0, stream>>>(T, phi, W2_fr, b2, W3, b3, s_m,
                                              m_ids, a_ids, dist, genre, spk, out);
}

// Round 4
// 126.528 us; speedup vs baseline: 2.8121x; 1.2011x over previous
//
#include <hip/hip_runtime.h>

typedef short bf16x8 __attribute__((ext_vector_type(8)));
typedef short bf16x4 __attribute__((ext_vector_type(4)));
typedef float f32x4  __attribute__((ext_vector_type(4)));

#define NSPAN 2000
#define DSPAN 1220
#define NPAIR 65536
#define HID   150
#define HP    160          // padded hidden width
#define TW    320          // T row: [0,160) A-proj, [160,320) B-proj
#define NKS   78           // total k-steps of 32 (K = 2496 = 2 x 1248)
#define NKH   39           // k-steps per half (g half / g^2 half)
#define NMT   128          // 2048/16 row tiles
#define NNT   20           // 320/16 col tiles
#define KC    6            // k-split chunks (78 = 6*13)
#define H1S   168          // h1 bf16 row stride (336 B, 16B aligned)
#define NCMB  189          // 9*7*3 phi combos

// prep_all grid sections
#define GA 1248            // A-fragments
#define GB 390             // Wc-fragments
#define GC 119             // combo phi table (189*160 = 30240)
#define GD 13              // W2 fragments (3200)
#define GE 160             // zero T (160000 float4)

static __device__ __forceinline__ short f2bf(float x) {
  unsigned u = __builtin_bit_cast(unsigned, x);
  u = (u + 0x7FFFu + ((u >> 16) & 1u)) >> 16;   // RNE
  return (short)u;
}

// ---------------- prep_all: everything except the two GEMMs ----------------
// A-frag:  offset ((mt*78+ks)*64+l)*8+i <-> A[mt*16+(l&15)][ks*32+(l>>4)*8+i]
//          A = [g pad->1248 | g^2 pad->1248]
// Wc-frag: offset ((nt*78+ks)*64+l)*8+i <-> Wc[ks*32+(l>>4)*8+i][nt*16+(l&15)]
//          Wc k<1248: [W1a | 0 | W1b | 0]; k in [1248,2468): [0 | 0 | W1c | 0]
// combo:   [(bb*7+genre)*3+spk][j] = b1[j] + de.W1d + ge.W1g + se.W1s
// W2-frag: offset ((jt*5+ks)*64+l)*8+i <-> W2[ks*32+(l>>4)*8+i][jt*16+(l&15)]
__global__ __launch_bounds__(256)
void prep_all(const float* __restrict__ g, const float* __restrict__ W1,
              const float* __restrict__ b1, const float* __restrict__ de,
              const float* __restrict__ ge, const float* __restrict__ se,
              const float* __restrict__ W2, short* __restrict__ A_fr,
              short* __restrict__ Wc_fr, float* __restrict__ combo,
              short* __restrict__ W2_fr, float* __restrict__ T) {
  int b = blockIdx.x;
  int t = threadIdx.x;
  if (b < GA) {                               // ---- A fragments ----
    int tid = b * 256 + t;                    // 1248*256 = 128*39*64 exact
    int l  = tid & 63;
    int t2 = tid >> 6;
    int ks = t2 % NKH;
    int mt = t2 / NKH;
    int m  = mt * 16 + (l & 15);
    int k0 = ks * 32 + ((l >> 4) << 3);
    float x[8];
    if (m < NSPAN && k0 + 8 <= DSPAN) {       // g rows 16B-aligned (1220*4 % 16 == 0)
      float4 f0 = *(const float4*)&g[m * DSPAN + k0];
      float4 f1 = *(const float4*)&g[m * DSPAN + k0 + 4];
      x[0]=f0.x; x[1]=f0.y; x[2]=f0.z; x[3]=f0.w;
      x[4]=f1.x; x[5]=f1.y; x[6]=f1.z; x[7]=f1.w;
    } else {
#pragma unroll
      for (int i = 0; i < 8; ++i) {
        int k = k0 + i;
        x[i] = (m < NSPAN && k < DSPAN) ? g[m * DSPAN + k] : 0.f;
      }
    }
    short v1[8], v2[8];
#pragma unroll
    for (int i = 0; i < 8; ++i) { v1[i] = f2bf(x[i]); v2[i] = f2bf(x[i] * x[i]); }
    size_t o1 = ((size_t)(mt * NKS + ks) * 64 + l) * 8;
    *(bf16x8*)(A_fr + o1) = *(const bf16x8*)v1;
    *(bf16x8*)(A_fr + o1 + (size_t)NKH * 512) = *(const bf16x8*)v2;
  } else if (b < GA + GB) {                   // ---- Wc fragments ----
    int tid = (b - GA) * 256 + t;             // 390*256 = 20*78*64 exact
    int l  = tid & 63;
    int t2 = tid >> 6;
    int ks = t2 % NKS;
    int nt = t2 / NKS;
    int n  = nt * 16 + (l & 15);
    int k0 = ks * 32 + ((l >> 4) << 3);
    short v[8];
#pragma unroll
    for (int i = 0; i < 8; ++i) {
      int k = k0 + i;
      float x = 0.f;
      if (n < HID) {
        if (k < DSPAN)                     x = W1[k * HID + n];
      } else if (n >= HP && n < HP + HID) {
        int j = n - HP;
        if (k < DSPAN)                     x = W1[(DSPAN + k) * HID + j];
        else if (k >= 1248 && k < 2468)    x = W1[(1192 + k) * HID + j];
      }
      v[i] = f2bf(x);
    }
    *(bf16x8*)(Wc_fr + (size_t)tid * 8) = *(const bf16x8*)v;
  } else if (b < GA + GB + GC) {              // ---- combined phi table ----
    int idx = (b - GA - GB) * 256 + t;
    if (idx < NCMB * HP) {
      int c = idx / HP;
      int j = idx - c * HP;
      float v = 0.f;
      if (j < HID) {
        int si = c % 3;
        int t2 = c / 3;
        int gi = t2 % 7;
        int bi = t2 / 7;
        v = b1[j];
        const float* dp = de + bi * 20;
        const float* gp = ge + gi * 20;
        const float* sp = se + si * 20;
#pragma unroll
        for (int e = 0; e < 20; ++e) {
          v += dp[e] * W1[(3660 + e) * HID + j];
          v += gp[e] * W1[(3680 + e) * HID + j];
          v += sp[e] * W1[(3700 + e) * HID + j];
        }
      }
      combo[idx] = v;
    }
  } else if (b < GA + GB + GC + GD) {         // ---- W2 fragments ----
    int tid = (b - GA - GB - GC) * 256 + t;
    if (tid < 3200) {
      int l  = tid & 63;
      int t2 = tid >> 6;
      int ks = t2 % 5;
      int jt = t2 / 5;
      int n  = jt * 16 + (l & 15);
      int k0 = ks * 32 + ((l >> 4) << 3);
      short v[8];
#pragma unroll
      for (int i = 0; i < 8; ++i) {
        int k = k0 + i;
        float x = (k < HID && n < HID) ? W2[k * HID + n] : 0.f;
        v[i] = f2bf(x);
      }
      *(bf16x8*)(W2_fr + (size_t)tid * 8) = *(const bf16x8*)v;
    }
  } else {                                    // ---- zero T ----
    int idx = (b - GA - GB - GC - GD) * 256 + t;
    f32x4 z = {0.f, 0.f, 0.f, 0.f};
    if (idx < NSPAN * TW / 4) ((f32x4*)T)[idx] = z;
  }
}

// ---------- span GEMM: T += A_cat @ Wc, K-split x6, fp32 atomicAdd ----------
__global__ __launch_bounds__(256)
void span_gemm(const short* __restrict__ A_fr, const short* __restrict__ Wc_fr,
               float* __restrict__ T) {
  int t = threadIdx.x, w = t >> 6, l = t & 63;
  int mt  = blockIdx.y * 4 + w;
  int ntb = blockIdx.x * 4;
  int ksb = blockIdx.z * 13;
  const short* pa = A_fr + ((size_t)(mt * NKS + ksb) * 64 + l) * 8;
  const short* pb = Wc_fr + ((size_t)(ntb * NKS + ksb) * 64 + l) * 8;
  f32x4 a0 = {0.f, 0.f, 0.f, 0.f}, a1 = a0, a2 = a0, a3 = a0;
#pragma unroll
  for (int ks = 0; ks < 13; ++ks) {
    bf16x8 a  = *(const bf16x8*)pa;
    bf16x8 b0 = *(const bf16x8*)pb;
    bf16x8 b1 = *(const bf16x8*)(pb + (size_t)NKS * 512);
    bf16x8 b2 = *(const bf16x8*)(pb + (size_t)2 * NKS * 512);
    bf16x8 b3 = *(const bf16x8*)(pb + (size_t)3 * NKS * 512);
    a0 = __builtin_amdgcn_mfma_f32_16x16x32_bf16(a, b0, a0, 0, 0, 0);
    a1 = __builtin_amdgcn_mfma_f32_16x16x32_bf16(a, b1, a1, 0, 0, 0);
    a2 = __builtin_amdgcn_mfma_f32_16x16x32_bf16(a, b2, a2, 0, 0, 0);
    a3 = __builtin_amdgcn_mfma_f32_16x16x32_bf16(a, b3, a3, 0, 0, 0);
    pa += 512; pb += 512;
  }
  int col = l & 15, row4 = (l >> 4) << 2;
  f32x4 acc[4] = {a0, a1, a2, a3};
#pragma unroll
  for (int r = 0; r < 4; ++r) {
    int m = mt * 16 + row4 + r;
    if (m < NSPAN) {
#pragma unroll
      for (int j = 0; j < 4; ++j)
        atomicAdd(&T[m * TW + (ntb + j) * 16 + col], acc[j][r]);
    }
  }
}

// ---------- pair kernel: gather h1 -> bf16 LDS -> MFMA layer2 -> score ----------
__global__ __launch_bounds__(256)
void pair_kernel(const float* __restrict__ T, const float* __restrict__ combo,
                 const short* __restrict__ W2_fr,
                 const float* __restrict__ b2, const float* __restrict__ W3,
                 const float* __restrict__ b3, const float* __restrict__ s_m,
                 const int* __restrict__ m_ids, const int* __restrict__ a_ids,
                 const int* __restrict__ dist, const int* __restrict__ genre,
                 const int* __restrict__ spk, float* __restrict__ out) {
  __shared__ short h1s[64 * H1S];
  __shared__ float w3s[HP], b2s[HP], sm2[64];
  __shared__ int mi[64], ai[64], co[64];

  int t = threadIdx.x;
  int base = blockIdx.x * 64;

  if (t < 64) {
    int p = base + t;
    int m = m_ids[p], a = a_ids[p];
    mi[t] = m; ai[t] = a;
    sm2[t] = s_m[m] + s_m[a];
    int d = dist[p];
    int bb = (d >= 2) + (d >= 3) + (d >= 4) + (d >= 5) + (d >= 8) +
             (d >= 16) + (d >= 32) + (d >= 64);
    co[t] = ((bb * 7 + genre[p]) * 3 + spk[p]) * HP;
  }
  if (t < HP) {
    w3s[t] = (t < HID) ? W3[t] : 0.f;
    b2s[t] = (t < HID) ? b2[t] : 0.f;
  }
  float b3v = b3[0];
  __syncthreads();

  // h1 = relu(T_A[m] + T_B[a] + combo), float4-vectorized (pad cols exact 0)
  for (int idx = t; idx < 64 * 40; idx += 256) {
    int p = idx / 40;
    int j = (idx - p * 40) * 4;
    const float4 vm = *(const float4*)&T[mi[p] * TW + j];
    const float4 va = *(const float4*)&T[ai[p] * TW + HP + j];
    const float4 fc = *(const float4*)&combo[co[p] + j];
    bf16x4 r;
    r[0] = f2bf(fmaxf(vm.x + va.x + fc.x, 0.f));
    r[1] = f2bf(fmaxf(vm.y + va.y + fc.y, 0.f));
    r[2] = f2bf(fmaxf(vm.z + va.z + fc.z, 0.f));
    r[3] = f2bf(fmaxf(vm.w + va.w + fc.w, 0.f));
    *(bf16x4*)&h1s[p * H1S + j] = r;
  }
  __syncthreads();

  int w = t >> 6, l = t & 63;
  const short* hrow = h1s + (w * 16 + (l & 15)) * H1S + ((l >> 4) << 3);
  bf16x8 af[5];
#pragma unroll
  for (int ks = 0; ks < 5; ++ks) af[ks] = *(const bf16x8*)(hrow + ks * 32);

  f32x4 acc[10];
#pragma unroll
  for (int jt = 0; jt < 10; ++jt) acc[jt] = {0.f, 0.f, 0.f, 0.f};

  const short* pw = W2_fr + l * 8;
#pragma unroll
  for (int jt = 0; jt < 10; ++jt) {
#pragma unroll
    for (int ks = 0; ks < 5; ++ks) {
      bf16x8 bfr = *(const bf16x8*)(pw + (size_t)(jt * 5 + ks) * 512);
      acc[jt] = __builtin_amdgcn_mfma_f32_16x16x32_bf16(af[ks], bfr, acc[jt], 0, 0, 0);
    }
  }

  float part[4] = {0.f, 0.f, 0.f, 0.f};
  int cl = l & 15;
#pragma unroll
  for (int jt = 0; jt < 10; ++jt) {
    int n = jt * 16 + cl;
    float w3v = w3s[n], b2v = b2s[n];
#pragma unroll
    for (int r = 0; r < 4; ++r) part[r] += fmaxf(acc[jt][r] + b2v, 0.f) * w3v;
  }
#pragma unroll
  for (int off = 8; off >= 1; off >>= 1) {
#pragma unroll
    for (int r = 0; r < 4; ++r) part[r] += __shfl_xor(part[r], off, 64);
  }
  if (cl == 0) {
    int rowb = (l >> 4) << 2;
#pragma unroll
    for (int r = 0; r < 4; ++r) {
      int p = w * 16 + rowb + r;
      out[base + p] = sm2[p] + part[r] + b3v;
    }
  }
}

extern "C" void kernel_launch(void* const* d_in, const int* in_sizes, int n_in,
                              void* d_out, int out_size, void* d_ws, size_t ws_size,
                              hipStream_t stream) {
  const float* g     = (const float*)d_in[0];
  const float* s_m   = (const float*)d_in[1];
  const int*   m_ids = (const int*)d_in[2];
  const int*   a_ids = (const int*)d_in[3];
  const int*   dist  = (const int*)d_in[4];
  const int*   genre = (const int*)d_in[5];
  const int*   spk   = (const int*)d_in[6];
  const float* de    = (const float*)d_in[7];
  const float* ge    = (const float*)d_in[8];
  const float* se    = (const float*)d_in[9];
  const float* W1    = (const float*)d_in[10];
  const float* b1    = (const float*)d_in[11];
  const float* W2    = (const float*)d_in[12];
  const float* b2    = (const float*)d_in[13];
  const float* W3    = (const float*)d_in[14];
  const float* b3    = (const float*)d_in[15];
  float* out = (float*)d_out;

  float* T     = (float*)d_ws;                    // 2000*320 f32 = 2.56 MB
  float* combo = T + NSPAN * TW;                  // 189*160 f32 (16B-aligned)
  short* A_fr  = (short*)(combo + NCMB * HP);     // 128*78*512 bf16 = 10.22 MB
  short* Wc_fr = A_fr + (size_t)NMT * NKS * 512;  // 20*78*512 bf16 = 1.60 MB
  short* W2_fr = Wc_fr + (size_t)NNT * NKS * 512; // 3200*8 bf16

  prep_all<<<GA + GB + GC + GD + GE, 256, 0, stream>>>(
      g, W1, b1, de, ge, se, W2, A_fr, Wc_fr, combo, W2_fr, T);
  span_gemm<<<dim3(5, 32, KC), 256, 0, stream>>>(A_fr, Wc_fr, T);
  pair_kernel<<<NPAIR / 64, 256, 0, stream>>>(T, combo, W2_fr, b2, W3, b3, s_m,
                                              m_ids, a_ids, dist, genre, spk, out);
}